// Round 2
// baseline (797.233 us; speedup 1.0000x reference)
//
#include <hip/hip_runtime.h>

// ---------------------------------------------------------------------------
// RelationalDynamics fp32 pipeline for MI355X.
// B=2048, K=16, Z=128, DIM=256, BK_ALL = B*K = 32768 rows.
//
// Algebra: eff = elu(h_i@WeL.T + h_j@WeR.T + be)  with
//   WeL = We[:, :128]+We[:,128:256], WeR = We[:,256:384]+We[:,384:512]
// => precompute U=h@WeL.T, V=h@WeR.T per object; pairs become elementwise.
// rel = h@(WcA).T + E@(WcB).T + bc with WcA = Wc[:, :128]+Wc[:,128:256].
// ---------------------------------------------------------------------------

__device__ __forceinline__ float eluf(float x) { return x > 0.0f ? x : expm1f(x); }
__device__ __forceinline__ float sigmoidf_(float x) { return 1.0f / (1.0f + expf(-x)); }

// ------------------------- weight prep -------------------------------------
// WUVT [128][1024]: WUVT[d][o] = (o<512) ? We[o][d]+We[o][d+128]
//                                        : We[o-512][d+256]+We[o-512][d+384]
// Wrel [128][640]:  Wrel[o][c] = (c<128) ? Wc[o][c]+Wc[o][c+128] : Wc[o][c+128]
// Wlsh [384][128]:  rows = [Wl; Ws; Wh];  blsh[384] = [bl; bs; bh]
__global__ __launch_bounds__(256) void prep_kernel(
    const float* __restrict__ We, const float* __restrict__ Wc,
    const float* __restrict__ Wl, const float* __restrict__ Wsc,
    const float* __restrict__ Wh, const float* __restrict__ bl,
    const float* __restrict__ bs, const float* __restrict__ bh,
    float* __restrict__ WUVT, float* __restrict__ Wrel,
    float* __restrict__ Wlsh, float* __restrict__ blsh)
{
  int idx = blockIdx.x * 256 + threadIdx.x;
  if (idx < 131072) {
    int d = idx >> 10, o = idx & 1023;
    float v;
    if (o < 512) v = We[o * 512 + d] + We[o * 512 + d + 128];
    else { int oo = o - 512; v = We[oo * 512 + d + 256] + We[oo * 512 + d + 384]; }
    WUVT[idx] = v;
  } else if (idx < 212992) {               // 131072 + 81920
    int j = idx - 131072; int o = j / 640, c = j - o * 640;
    Wrel[j] = (c < 128) ? (Wc[o * 768 + c] + Wc[o * 768 + c + 128])
                        : Wc[o * 768 + c + 128];
  } else if (idx < 262144) {               // + 49152
    int j = idx - 212992; int o = j >> 7, c = j & 127;
    Wlsh[j] = (o < 128) ? Wl[o * 128 + c]
            : (o < 256) ? Wsc[(o - 128) * 128 + c]
                        : Wh[(o - 256) * 128 + c];
  } else if (idx < 262528) {
    int j = idx - 262144;
    blsh[j] = (j < 128) ? bl[j] : (j < 256) ? bs[j - 128] : bh[j - 256];
  }
}

// ------------------------- generic tiled GEMM ------------------------------
// C[M,N] = act(A[M,K] @ W.T + bias),  W is [N][K] row-major (torch layout).
// 64x64 tile, 256 threads, 4x4 microtile, BK=32. grid = (M/64, N/64).
// ACT: 0 none, 1 elu. OUTMODE: 0 -> C[r*ldc+c];
// OUTMODE 1 -> c<256: C[r*256+c] (loc|scale), c>=256: C2[r*128+c-256] (h_out).
template<int ACT, int OUTMODE>
__global__ __launch_bounds__(256) void gemm_kernel(
    const float* __restrict__ A, int lda,
    const float* __restrict__ W, int K,
    const float* __restrict__ bias,
    float* __restrict__ C, int ldc, float* __restrict__ C2)
{
  __shared__ float As[32][68];   // stride 68: float4-aligned, conflict-light
  __shared__ float Bs[32][68];
  const int t = threadIdx.x;
  const int tc = t & 15, tr = t >> 4;
  const int row0 = blockIdx.x * 64, col0 = blockIdx.y * 64;
  float acc[4][4] = {{0.f,0.f,0.f,0.f},{0.f,0.f,0.f,0.f},
                     {0.f,0.f,0.f,0.f},{0.f,0.f,0.f,0.f}};
  for (int kk = 0; kk < K; kk += 32) {
#pragma unroll
    for (int i = 0; i < 2; ++i) {
      int f = t + i * 256;                 // 0..511
      int r = f >> 3, k4 = (f & 7) << 2;   // r 0..63, k4 0..28
      float4 va = *(const float4*)(A + (size_t)(row0 + r) * lda + kk + k4);
      As[k4 + 0][r] = va.x; As[k4 + 1][r] = va.y;
      As[k4 + 2][r] = va.z; As[k4 + 3][r] = va.w;
      float4 vw = *(const float4*)(W + (size_t)(col0 + r) * K + kk + k4);
      Bs[k4 + 0][r] = vw.x; Bs[k4 + 1][r] = vw.y;
      Bs[k4 + 2][r] = vw.z; Bs[k4 + 3][r] = vw.w;
    }
    __syncthreads();
#pragma unroll
    for (int k = 0; k < 32; ++k) {
      float4 a = *(const float4*)&As[k][tr << 2];
      float4 b = *(const float4*)&Bs[k][tc << 2];
      acc[0][0] = fmaf(a.x, b.x, acc[0][0]); acc[0][1] = fmaf(a.x, b.y, acc[0][1]);
      acc[0][2] = fmaf(a.x, b.z, acc[0][2]); acc[0][3] = fmaf(a.x, b.w, acc[0][3]);
      acc[1][0] = fmaf(a.y, b.x, acc[1][0]); acc[1][1] = fmaf(a.y, b.y, acc[1][1]);
      acc[1][2] = fmaf(a.y, b.z, acc[1][2]); acc[1][3] = fmaf(a.y, b.w, acc[1][3]);
      acc[2][0] = fmaf(a.z, b.x, acc[2][0]); acc[2][1] = fmaf(a.z, b.y, acc[2][1]);
      acc[2][2] = fmaf(a.z, b.z, acc[2][2]); acc[2][3] = fmaf(a.z, b.w, acc[2][3]);
      acc[3][0] = fmaf(a.w, b.x, acc[3][0]); acc[3][1] = fmaf(a.w, b.y, acc[3][1]);
      acc[3][2] = fmaf(a.w, b.z, acc[3][2]); acc[3][3] = fmaf(a.w, b.w, acc[3][3]);
    }
    __syncthreads();
  }
#pragma unroll
  for (int i = 0; i < 4; ++i) {
    int r = row0 + (tr << 2) + i;
    int c = col0 + (tc << 2);
    float4 v;
    float vv[4];
#pragma unroll
    for (int j = 0; j < 4; ++j) {
      float x = acc[i][j] + bias[c + j];
      if (ACT == 1) x = x > 0.f ? x : expm1f(x);
      vv[j] = x;
    }
    v.x = vv[0]; v.y = vv[1]; v.z = vv[2]; v.w = vv[3];
    if (OUTMODE == 0) {
      *(float4*)(C + (size_t)r * ldc + c) = v;
    } else {
      if (c < 256) *(float4*)(C + (size_t)r * 256 + c) = v;
      else         *(float4*)(C2 + (size_t)r * 128 + (c - 256)) = v;
    }
  }
}

// ------------------------- GRU gates ---------------------------------------
// h_new = (1-u)*n + u*h0 ; writes h_new into Acat[:, 0:128] (ldc=640)
__global__ __launch_bounds__(256) void gru_gates_kernel(
    const float* __restrict__ gi, const float* __restrict__ gh,
    const float* __restrict__ h0, float* __restrict__ Acat)
{
  int g = blockIdx.x * 256 + threadIdx.x;   // 32768*32 threads
  int r = g >> 5, c = (g & 31) << 2;
  const float* gir = gi + (size_t)r * 384;
  const float* ghr = gh + (size_t)r * 384;
  float4 ir  = *(const float4*)(gir + c);
  float4 iz  = *(const float4*)(gir + 128 + c);
  float4 in_ = *(const float4*)(gir + 256 + c);
  float4 hr  = *(const float4*)(ghr + c);
  float4 hz  = *(const float4*)(ghr + 128 + c);
  float4 hn  = *(const float4*)(ghr + 256 + c);
  float4 h   = *(const float4*)(h0 + (size_t)r * 128 + c);
  float4 o;
  {
    float rg = sigmoidf_(ir.x + hr.x), u = sigmoidf_(iz.x + hz.x);
    float n = tanhf(in_.x + rg * hn.x);
    o.x = (1.f - u) * n + u * h.x;
  }
  {
    float rg = sigmoidf_(ir.y + hr.y), u = sigmoidf_(iz.y + hz.y);
    float n = tanhf(in_.y + rg * hn.y);
    o.y = (1.f - u) * n + u * h.y;
  }
  {
    float rg = sigmoidf_(ir.z + hr.z), u = sigmoidf_(iz.z + hz.z);
    float n = tanhf(in_.z + rg * hn.z);
    o.z = (1.f - u) * n + u * h.z;
  }
  {
    float rg = sigmoidf_(ir.w + hr.w), u = sigmoidf_(iz.w + hz.w);
    float n = tanhf(in_.w + rg * hn.w);
    o.w = (1.f - u) * n + u * h.w;
  }
  *(float4*)(Acat + (size_t)r * 640 + c) = o;
}

// ------------------------- fused pair kernel -------------------------------
// One block (512 threads, 8 waves) per batch b. Computes U=h@WeL.T,
// V=h@WeR.T into LDS, att[p] for the 120 pairs, then
// E[k] = sum_m att*elu(U[i]+V[j]+be) written into Acat[:, 128:640].
// LDS ~77KB -> 2 blocks/CU -> 16 waves/CU (4/SIMD).
__global__ __launch_bounds__(512) void pair_kernel(
    float* __restrict__ Acat,
    const float* __restrict__ WUVT,   // [128][1024]
    const float* __restrict__ be, const float* __restrict__ Wa,
    const float* __restrict__ ba)
{
  __shared__ float h_lds[16][128];
  __shared__ float UV[16][1024];      // [k][0:512]=U, [k][512:1024]=V
  __shared__ float att_l[120];
  __shared__ int ii_l[120], jj_l[120];
  __shared__ float be_l[512], wa_l[512];
  const int b = blockIdx.x, t = threadIdx.x;

  {
    int k = t >> 5, c4 = (t & 31) << 2;   // 512 threads = 16k x 32 float4
    *(float4*)&h_lds[k][c4] = *(const float4*)(Acat + (size_t)(b * 16 + k) * 640 + c4);
  }
  if (t < 128) { *(float4*)&be_l[t << 2] = *(const float4*)(be + (t << 2)); }
  else if (t < 256) { int u = t - 128; *(float4*)&wa_l[u << 2] = *(const float4*)(Wa + (u << 2)); }
  else if (t >= 256 && t < 376) {
    int p = t - 256, i = 0, rem = p;
    while (rem >= 15 - i) { rem -= 15 - i; ++i; }
    ii_l[p] = i; jj_l[p] = i + 1 + rem;
  }
  __syncthreads();

  // ---- UV phase: thread t owns output cols {t, t+512} x 16 objects
  {
    float acc[16][2];
#pragma unroll
    for (int k = 0; k < 16; ++k) { acc[k][0] = 0.f; acc[k][1] = 0.f; }
#pragma unroll 4
    for (int d = 0; d < 128; ++d) {
      const float* wrow = WUVT + (size_t)d * 1024;
      float w0 = wrow[t], w1 = wrow[t + 512];
#pragma unroll
      for (int k = 0; k < 16; ++k) {
        float hv = h_lds[k][d];
        acc[k][0] = fmaf(hv, w0, acc[k][0]);
        acc[k][1] = fmaf(hv, w1, acc[k][1]);
      }
    }
#pragma unroll
    for (int k = 0; k < 16; ++k) {
      UV[k][t] = acc[k][0]; UV[k][t + 512] = acc[k][1];
    }
  }
  __syncthreads();

  const int w = t >> 6, l = t & 63;
  const float ba0 = ba[0];

  // ---- attention phase: wave w handles pairs w*15 .. w*15+14
  for (int q = 0; q < 15; ++q) {
    int p = w * 15 + q;
    int i = ii_l[p], j = jj_l[p];
    float s = 0.f;
#pragma unroll
    for (int u = 0; u < 2; ++u) {
      int d = (l << 3) + (u << 2);
      float4 uu = *(const float4*)&UV[i][d];
      float4 vv = *(const float4*)&UV[j][512 + d];
      float4 bb = *(const float4*)&be_l[d];
      float4 aa = *(const float4*)&wa_l[d];
      s = fmaf(eluf(uu.x + vv.x + bb.x), aa.x, s);
      s = fmaf(eluf(uu.y + vv.y + bb.y), aa.y, s);
      s = fmaf(eluf(uu.z + vv.z + bb.z), aa.z, s);
      s = fmaf(eluf(uu.w + vv.w + bb.w), aa.w, s);
    }
#pragma unroll
    for (int off = 32; off > 0; off >>= 1) s += __shfl_xor(s, off, 64);
    if (l == 0) att_l[p] = sigmoidf_(s + ba0);
  }
  __syncthreads();

  // ---- E phase: wave w owns k in {2w, 2w+1}; lane l owns d in [8l, 8l+8)
  float be8[8];
#pragma unroll
  for (int u = 0; u < 2; ++u) {
    float4 bb = *(const float4*)&be_l[(l << 3) + (u << 2)];
    be8[u*4+0] = bb.x; be8[u*4+1] = bb.y; be8[u*4+2] = bb.z; be8[u*4+3] = bb.w;
  }
  float ebuf[2][8];
#pragma unroll
  for (int kk = 0; kk < 2; ++kk)
#pragma unroll
    for (int u = 0; u < 8; ++u) ebuf[kk][u] = 0.f;
#pragma unroll
  for (int kk = 0; kk < 2; ++kk) {
    const int k = (w << 1) + kk;
    for (int m = 0; m < 16; ++m) {
      if (m == k) continue;
      int i = k < m ? k : m;
      int j = k < m ? m : k;
      int p = i * 15 - ((i * (i - 1)) >> 1) + (j - i - 1);
      float av = att_l[p];
#pragma unroll
      for (int u = 0; u < 2; ++u) {
        int d = (l << 3) + (u << 2);
        float4 uu = *(const float4*)&UV[i][d];
        float4 vv = *(const float4*)&UV[j][512 + d];
        ebuf[kk][u*4+0] = fmaf(av, eluf(uu.x + vv.x + be8[u*4+0]), ebuf[kk][u*4+0]);
        ebuf[kk][u*4+1] = fmaf(av, eluf(uu.y + vv.y + be8[u*4+1]), ebuf[kk][u*4+1]);
        ebuf[kk][u*4+2] = fmaf(av, eluf(uu.z + vv.z + be8[u*4+2]), ebuf[kk][u*4+2]);
        ebuf[kk][u*4+3] = fmaf(av, eluf(uu.w + vv.w + be8[u*4+3]), ebuf[kk][u*4+3]);
      }
    }
  }
#pragma unroll
  for (int kk = 0; kk < 2; ++kk) {
    const int k = (w << 1) + kk;
#pragma unroll
    for (int u = 0; u < 2; ++u) {
      float4 o;
      o.x = ebuf[kk][u*4+0]; o.y = ebuf[kk][u*4+1];
      o.z = ebuf[kk][u*4+2]; o.w = ebuf[kk][u*4+3];
      *(float4*)(Acat + (size_t)(b * 16 + k) * 640 + 128 + (l << 3) + (u << 2)) = o;
    }
  }
}

// ---------------------------------------------------------------------------
extern "C" void kernel_launch(void* const* d_in, const int* in_sizes, int n_in,
                              void* d_out, int out_size, void* d_ws, size_t ws_size,
                              hipStream_t stream)
{
  (void)in_sizes; (void)n_in; (void)out_size; (void)ws_size;
  const float* z     = (const float*)d_in[0];
  const float* h0    = (const float*)d_in[1];
  const float* W_obj = (const float*)d_in[2];
  const float* b_obj = (const float*)d_in[3];
  const float* Wih   = (const float*)d_in[4];
  const float* bih   = (const float*)d_in[5];
  const float* Whh   = (const float*)d_in[6];
  const float* bhh   = (const float*)d_in[7];
  const float* We    = (const float*)d_in[8];
  const float* be    = (const float*)d_in[9];
  const float* Wa    = (const float*)d_in[10];
  const float* ba    = (const float*)d_in[11];
  const float* Wc    = (const float*)d_in[12];
  const float* bc    = (const float*)d_in[13];
  const float* Wl    = (const float*)d_in[14];
  const float* bl    = (const float*)d_in[15];
  const float* Wsc   = (const float*)d_in[16];
  const float* bs    = (const float*)d_in[17];
  const float* Wh    = (const float*)d_in[18];
  const float* bh    = (const float*)d_in[19];

  float* ws  = (float*)d_ws;
  float* out = (float*)d_out;

  // workspace layout (floats); rel aliases x (x dead after gi GEMM)
  float* x    = ws;                  //  8,388,608  [32768][256]
  float* gi   = ws + 8388608;        // 12,582,912  [32768][384]
  float* gh   = ws + 20971520;       // 12,582,912  [32768][384]
  float* Acat = ws + 33554432;       // 20,971,520  [32768][640] = [h_new | E]
  float* WUVT = ws + 54525952;       //    131,072  [128][1024]
  float* Wrel = ws + 54657024;       //     81,920  [128][640]
  float* Wlsh = ws + 54738944;       //     49,152  [384][128]
  float* blsh = ws + 54788096;       //        384
  float* rel  = x;                   //  4,194,304  [32768][128]

  prep_kernel<<<1026, 256, 0, stream>>>(We, Wc, Wl, Wsc, Wh, bl, bs, bh,
                                        WUVT, Wrel, Wlsh, blsh);
  // x = elu(z @ W_obj.T + b_obj)            [32768,128]x[256,128]
  gemm_kernel<1,0><<<dim3(512, 4), 256, 0, stream>>>(z, 128, W_obj, 128, b_obj, x, 256, nullptr);
  // gi = x @ Wih.T + bih                    [32768,256]x[384,256]
  gemm_kernel<0,0><<<dim3(512, 6), 256, 0, stream>>>(x, 256, Wih, 256, bih, gi, 384, nullptr);
  // gh = h0 @ Whh.T + bhh                   [32768,128]x[384,128]
  gemm_kernel<0,0><<<dim3(512, 6), 256, 0, stream>>>(h0, 128, Whh, 128, bhh, gh, 384, nullptr);
  // GRU gates -> h_new into Acat[:,0:128]
  gru_gates_kernel<<<4096, 256, 0, stream>>>(gi, gh, h0, Acat);
  // per-batch: U,V -> att -> E into Acat[:,128:640]
  pair_kernel<<<2048, 512, 0, stream>>>(Acat, WUVT, be, Wa, ba);
  // rel = Acat @ Wrel.T + bc                [32768,640]x[128,640]
  gemm_kernel<0,0><<<dim3(512, 2), 256, 0, stream>>>(Acat, 640, Wrel, 640, bc, rel, 128, nullptr);
  // [loc|scale|h_out] = rel @ Wlsh.T + blsh, scattered into d_out
  gemm_kernel<0,1><<<dim3(512, 6), 256, 0, stream>>>(rel, 128, Wlsh, 128, blsh, out, 0, out + 8388608);
}